// Round 2
// baseline (867.591 us; speedup 1.0000x reference)
//
#include <hip/hip_runtime.h>
#include <cstdint>
#include <cstddef>

typedef unsigned short u16;
typedef unsigned int   u32;
typedef unsigned long long u64;
typedef __attribute__((ext_vector_type(8))) short short8;   // 8 bf16 = 4 VGPR
typedef __attribute__((ext_vector_type(4))) float f32x4;

#define M_ROWS 16384
#define N_COLS 256
#define IN_F   1024
#define K_SPL  8192   // 1024 features * 8 basis
#define K_TOT  9216   // + 1024 base (silu) features
// BK=64 chunks: 144 total (128 spline chunks of 8 features, 16 base chunks of 64 feats)
#define NCHUNK 144
#define SPLITK 4
#define CPB    (NCHUNK / SPLITK)   // 36 chunks per block

// ---------- helpers ----------
__device__ __forceinline__ u32 f2bf1(float f) {          // f32 -> bf16 bits, RNE
  u32 u = __float_as_uint(f);
  u += 0x7fffu + ((u >> 16) & 1u);
  return u >> 16;
}
__device__ __forceinline__ u32 pk2(float a, float b) {
  return f2bf1(a) | (f2bf1(b) << 16);
}
__device__ __forceinline__ float silu(float v) {
  return v * __builtin_amdgcn_rcpf(1.f + __expf(-v));
}

// 8 bf16 cubic B-spline basis values for one x, packed as uint4 (16B).
// u = 2.5x + 5.5; basis_j(x) = N3(u - j); 4 nonzero wts scattered via funnel shift.
__device__ __forceinline__ uint4 basis8(float xv) {
  float u = fmaf(xv, 2.5f, 5.5f);
  int i0 = (int)u;
  float fr = u - (float)i0;
  float fr2 = fr * fr, fr3 = fr2 * fr;
  float om  = 1.f - fr;
  float om3 = om * om * om;
  float w0 = om3 * (1.f / 6.f);
  float w3 = fr3 * (1.f / 6.f);
  float w1 = fmaf(fr3, 0.5f, fmaf(fr2, -1.f, 2.f / 3.f));
  float w2 = fmaf(fr + fr2 - fr3, 0.5f, 1.f / 6.f);
  u64 W = (u64)pk2(w0, w1) | ((u64)pk2(w2, w3) << 32);
  if (!(u >= 0.f && u < 11.f)) W = 0ull;
  int s = (i0 - 3) * 16;
  u64 lo, hi;
  if (s >= 64)      { int r = s - 64; lo = 0ull; hi = (r < 64) ? (W << r) : 0ull; }
  else if (s > 0)   { lo = W << s;    hi = W >> (64 - s); }
  else if (s == 0)  { lo = W;         hi = 0ull; }
  else              { int r = -s;     lo = (r < 64) ? (W >> r) : 0ull; hi = 0ull; }
  uint4 o;
  o.x = (u32)lo; o.y = (u32)(lo >> 32); o.z = (u32)hi; o.w = (u32)(hi >> 32);
  return o;
}

// ---------- kernel 1: pack [spline_weight | base_weight] -> bf16, (256 x 9216) row-major ----------
__global__ void pack_weights(const float* __restrict__ bw, const float* __restrict__ sw,
                             u16* __restrict__ Bp) {
  int o  = blockIdx.y;
  int k4 = (blockIdx.x * blockDim.x + threadIdx.x) * 4;
  const float* src = (k4 < K_SPL) ? (sw + (size_t)o * K_SPL + k4)
                                  : (bw + (size_t)o * IN_F + (k4 - K_SPL));
  float a = src[0], b = src[1], c = src[2], d = src[3];
  uint2 v; v.x = pk2(a, b); v.y = pk2(c, d);
  *(uint2*)(Bp + (size_t)o * K_TOT + k4) = v;
}

// ---------- kernel 2: fused KAN GEMM ----------
// BM=128 BN=128 BK=64, 256 thr (4 waves @ 64x64), split-K=4 -> 1024 blocks, 4 blocks/CU.
// LDS layout (As and Bs): 128 rows x 8 chunks of 16B; chunk c of row r stored at
// slot r*8 + (c ^ (r&7))  -- XOR swizzle keeps bank spread even (row stride 128B
// would otherwise alias all rows to the same banks) while the Bs slot index stays
// contiguous in tid for global_load_lds.
__global__ __launch_bounds__(256, 4)
void kan_gemm(const float* __restrict__ x, const u16* __restrict__ Bp,
              float* __restrict__ out) {
  __shared__ __align__(16) u16 As[128 * 64];
  __shared__ __align__(16) u16 Bs[128 * 64];

  const int tid  = threadIdx.x;
  const int lane = tid & 63;
  const int w    = tid >> 6;
  const int wm   = w & 1;
  const int wn   = w >> 1;

  const int bid  = blockIdx.x;        // 1024
  const int kid  = bid & 3;
  const int nb   = (bid >> 2) & 1;
  const int mb   = bid >> 3;          // 0..127
  const int row0 = mb * 128;
  const int n0   = nb * 128;
  const int cs   = kid * CPB, c1 = cs + CPB;

  f32x4 acc[4][4];
#pragma unroll
  for (int i = 0; i < 4; ++i)
#pragma unroll
    for (int j = 0; j < 4; ++j)
      acc[i][j] = (f32x4){0.f, 0.f, 0.f, 0.f};

  const int sr = tid >> 1;            // staging row 0..127
  const int sh = tid & 1;             // which half of the 64-k row

  // fragment read offsets (u16 index), swizzled
  const int lm = lane & 15;
  const int kg = lane >> 4;
  int a_off[2][4], b_off[2][4];
#pragma unroll
  for (int t = 0; t < 4; ++t) {
    int ra = wm * 64 + t * 16 + lm;
    int rb = wn * 64 + t * 16 + lm;
#pragma unroll
    for (int h = 0; h < 2; ++h) {
      int c = h * 4 + kg;
      a_off[h][t] = ra * 64 + ((c ^ (ra & 7)) * 8);
      b_off[h][t] = rb * 64 + ((c ^ (rb & 7)) * 8);
    }
  }

  float4 pa[8];

  auto LOADX = [&](int c) {
    if (c < 128) {
      pa[0] = *(const float4*)(x + (size_t)(row0 + sr) * IN_F + c * 8 + sh * 4);
    } else {
      const float* xp = x + (size_t)(row0 + sr) * IN_F + (c - 128) * 64 + sh * 32;
#pragma unroll
      for (int i = 0; i < 8; ++i) pa[i] = *(const float4*)(xp + i * 4);
    }
  };

  auto BUILD = [&](int c) {
    if (c < 128) {
      float v0 = pa[0].x, v1 = pa[0].y, v2 = pa[0].z, v3 = pa[0].w;
      float vv[4] = {v0, v1, v2, v3};
#pragma unroll
      for (int q = 0; q < 4; ++q) {
        int cc = sh * 4 + q;
        *(uint4*)(As + sr * 64 + ((cc ^ (sr & 7)) * 8)) = basis8(vv[q]);
      }
    } else {
#pragma unroll
      for (int q = 0; q < 4; ++q) {
        float4 u0 = pa[2 * q], u1 = pa[2 * q + 1];
        uint4 qq;
        qq.x = pk2(silu(u0.x), silu(u0.y));
        qq.y = pk2(silu(u0.z), silu(u0.w));
        qq.z = pk2(silu(u1.x), silu(u1.y));
        qq.w = pk2(silu(u1.z), silu(u1.w));
        int cc = sh * 4 + q;
        *(uint4*)(As + sr * 64 + ((cc ^ (sr & 7)) * 8)) = qq;
      }
    }
  };

  auto STAGEB = [&](int c) {
#pragma unroll
    for (int it = 0; it < 4; ++it) {
      int s = tid + it * 256;
      int r_ = s >> 3, cc = (s & 7) ^ (r_ & 7);
      const u16* gp = Bp + (size_t)(n0 + r_) * K_TOT + c * 64 + cc * 8;
      __builtin_amdgcn_global_load_lds((const __attribute__((address_space(1))) void*)gp,
                                       (__attribute__((address_space(3))) void*)(Bs + s * 8),
                                       16, 0, 0);
    }
  };

  LOADX(cs);
  for (int c = cs; c < c1; ++c) {
    BUILD(c);
    STAGEB(c);
    if (c + 1 < c1) LOADX(c + 1);
    __syncthreads();
#pragma unroll
    for (int h = 0; h < 2; ++h) {
      short8 af[4], bf[4];
#pragma unroll
      for (int t = 0; t < 4; ++t) {
        af[t] = *(const short8*)(As + a_off[h][t]);
        bf[t] = *(const short8*)(Bs + b_off[h][t]);
      }
#pragma unroll
      for (int i = 0; i < 4; ++i)
#pragma unroll
        for (int j = 0; j < 4; ++j)
          acc[i][j] = __builtin_amdgcn_mfma_f32_16x16x32_bf16(af[i], bf[j], acc[i][j], 0, 0, 0);
    }
    __syncthreads();
  }

  // ---- epilogue: C/D layout col=lane&15, row=(lane>>4)*4+reg; split-K -> atomic add ----
  const int lc = lane & 15;
  const int lr = (lane >> 4) * 4;
#pragma unroll
  for (int i = 0; i < 4; ++i) {
#pragma unroll
    for (int j = 0; j < 4; ++j) {
      int gr = row0 + wm * 64 + i * 16 + lr;
      int gc = n0 + wn * 64 + j * 16 + lc;
      float* po = out + (size_t)gr * N_COLS + gc;
#pragma unroll
      for (int r = 0; r < 4; ++r)
        unsafeAtomicAdd(po + (size_t)r * N_COLS, acc[i][j][r]);
    }
  }
}

extern "C" void kernel_launch(void* const* d_in, const int* in_sizes, int n_in,
                              void* d_out, int out_size, void* d_ws, size_t ws_size,
                              hipStream_t stream) {
  const float* x  = (const float*)d_in[0];   // 16384 x 1024
  const float* bw = (const float*)d_in[1];   // 256 x 1024
  const float* sw = (const float*)d_in[2];   // 256 x 8192
  float* out = (float*)d_out;                // 16384 x 256 f32
  u16* Bp = (u16*)d_ws;                      // 256 x 9216 bf16 = 4.5 MB

  hipMemsetAsync(d_out, 0, (size_t)M_ROWS * N_COLS * sizeof(float), stream);

  dim3 pgrid(K_TOT / 4 / 256, N_COLS);       // (9, 256)
  pack_weights<<<pgrid, 256, 0, stream>>>(bw, sw, Bp);

  kan_gemm<<<128 * 2 * SPLITK, 256, 0, stream>>>(x, Bp, out);
}

// Round 3
// 352.059 us; speedup vs baseline: 2.4643x; 2.4643x over previous
//
#include <hip/hip_runtime.h>
#include <cstdint>
#include <cstddef>

typedef unsigned short u16;
typedef unsigned int   u32;
typedef unsigned long long u64;
typedef __attribute__((ext_vector_type(8))) short short8;   // 8 bf16 = 4 VGPR
typedef __attribute__((ext_vector_type(4))) float f32x4;

#define M_ROWS 16384
#define N_COLS 256
#define IN_F   1024
#define K_SPL  8192   // 1024 features * 8 basis
#define K_TOT  9216   // + 1024 base (silu) features
// BK=64 chunks: 144 total (128 spline chunks of 8 features, 16 base chunks of 64 feats)
#define NCHUNK 144
#define CPG    36     // chunks per K-group (144 / (2 blocks-splitK * 2 groups))

// ---------- helpers ----------
__device__ __forceinline__ u32 f2bf1(float f) {          // f32 -> bf16 bits, RNE
  u32 u = __float_as_uint(f);
  u += 0x7fffu + ((u >> 16) & 1u);
  return u >> 16;
}
__device__ __forceinline__ u32 pk2(float a, float b) {
  return f2bf1(a) | (f2bf1(b) << 16);
}
__device__ __forceinline__ float silu(float v) {
  return v * __builtin_amdgcn_rcpf(1.f + __expf(-v));
}

// 8 bf16 cubic B-spline basis values for one x, packed as uint4 (16B).
// u = 2.5x + 5.5; basis_j(x) = N3(u - j); 4 nonzero wts scattered via funnel shift.
__device__ __forceinline__ uint4 basis8(float xv) {
  float u = fmaf(xv, 2.5f, 5.5f);
  int i0 = (int)u;
  float fr = u - (float)i0;
  float fr2 = fr * fr, fr3 = fr2 * fr;
  float om  = 1.f - fr;
  float om3 = om * om * om;
  float w0 = om3 * (1.f / 6.f);
  float w3 = fr3 * (1.f / 6.f);
  float w1 = fmaf(fr3, 0.5f, fmaf(fr2, -1.f, 2.f / 3.f));
  float w2 = fmaf(fr + fr2 - fr3, 0.5f, 1.f / 6.f);
  u64 W = (u64)pk2(w0, w1) | ((u64)pk2(w2, w3) << 32);
  if (!(u >= 0.f && u < 11.f)) W = 0ull;
  int s = (i0 - 3) * 16;
  u64 lo, hi;
  if (s >= 64)      { int r = s - 64; lo = 0ull; hi = (r < 64) ? (W << r) : 0ull; }
  else if (s > 0)   { lo = W << s;    hi = W >> (64 - s); }
  else if (s == 0)  { lo = W;         hi = 0ull; }
  else              { int r = -s;     lo = (r < 64) ? (W >> r) : 0ull; hi = 0ull; }
  uint4 o;
  o.x = (u32)lo; o.y = (u32)(lo >> 32); o.z = (u32)hi; o.w = (u32)(hi >> 32);
  return o;
}

// ---------- kernel 1: pack [spline_weight | base_weight] -> bf16, (256 x 9216) row-major ----------
__global__ void pack_weights(const float* __restrict__ bw, const float* __restrict__ sw,
                             u16* __restrict__ Bp) {
  int o  = blockIdx.y;
  int k4 = (blockIdx.x * blockDim.x + threadIdx.x) * 4;
  const float* src = (k4 < K_SPL) ? (sw + (size_t)o * K_SPL + k4)
                                  : (bw + (size_t)o * IN_F + (k4 - K_SPL));
  float a = src[0], b = src[1], c = src[2], d = src[3];
  uint2 v; v.x = pk2(a, b); v.y = pk2(c, d);
  *(uint2*)(Bp + (size_t)o * K_TOT + k4) = v;
}

// ---------- kernel 2: fused KAN GEMM ----------
// BM=128 BN=128 BK=64. 512 threads = 2 K-groups of 256 (4 waves @ 64x64 each);
// each group computes the full 128x128 tile over a K-quarter in private As/Bs,
// group1's accumulator is reduced into group0's via LDS, then ONE split-K=2
// atomic pass per cell (R1-proven benign: 8.4M atomics, writes ~2x out).
// kid partner blocks are 8 bids apart -> same XCD under round-robin dispatch,
// so atomic lines stay in one L2.
// LDS chunk swizzle: 16B chunk c of row r at slot r*8 + (c ^ (r&7)).
__global__ __launch_bounds__(512, 4)
void kan_gemm(const float* __restrict__ x, const u16* __restrict__ Bp,
              float* __restrict__ out) {
  __shared__ __align__(16) u16 smem[4 * 128 * 64];   // 64 KB: As[g0],As[g1],Bs[g0],Bs[g1]

  const int tid  = threadIdx.x;
  const int g    = tid >> 8;          // K-group 0/1
  const int ltid = tid & 255;
  const int lane = tid & 63;
  const int w    = (tid >> 6) & 3;    // wave within group
  const int wm   = w & 1;
  const int wn   = w >> 1;

  u16* As = smem + g * 8192;
  u16* Bs = smem + 16384 + g * 8192;

  // bid decode: kid partners are bid and bid+8 (same XCD, round-robin dispatch)
  const int bid  = blockIdx.x;        // 512
  const int mbl  = bid & 7;
  const int kid  = (bid >> 3) & 1;
  const int nb   = (bid >> 4) & 1;
  const int mbh  = bid >> 5;          // 0..15
  const int mb   = mbh * 8 + mbl;     // 0..127
  const int row0 = mb * 128;
  const int n0   = nb * 128;
  const int cs   = (kid * 2 + g) * CPG, c1 = cs + CPG;

  f32x4 acc[4][4];
#pragma unroll
  for (int i = 0; i < 4; ++i)
#pragma unroll
    for (int j = 0; j < 4; ++j)
      acc[i][j] = (f32x4){0.f, 0.f, 0.f, 0.f};

  const int sr = ltid >> 1;           // staging row 0..127
  const int sh = ltid & 1;            // which half of the 64-k row

  // fragment read offsets (u16 index within As/Bs), swizzled
  const int lm = lane & 15;
  const int kg = lane >> 4;
  int a_off[2][4], b_off[2][4];
#pragma unroll
  for (int t = 0; t < 4; ++t) {
    int ra = wm * 64 + t * 16 + lm;
    int rb = wn * 64 + t * 16 + lm;
#pragma unroll
    for (int h = 0; h < 2; ++h) {
      int c = h * 4 + kg;
      a_off[h][t] = ra * 64 + ((c ^ (ra & 7)) * 8);
      b_off[h][t] = rb * 64 + ((c ^ (rb & 7)) * 8);
    }
  }

  float4 pa[8];

  auto LOADX = [&](int c) {
    if (c < 128) {
      pa[0] = *(const float4*)(x + (size_t)(row0 + sr) * IN_F + c * 8 + sh * 4);
    } else {
      const float* xp = x + (size_t)(row0 + sr) * IN_F + (c - 128) * 64 + sh * 32;
#pragma unroll
      for (int i = 0; i < 8; ++i) pa[i] = *(const float4*)(xp + i * 4);
    }
  };

  auto BUILD = [&](int c) {
    if (c < 128) {
      float vv[4] = {pa[0].x, pa[0].y, pa[0].z, pa[0].w};
#pragma unroll
      for (int q = 0; q < 4; ++q) {
        int cc = sh * 4 + q;
        *(uint4*)(As + sr * 64 + ((cc ^ (sr & 7)) * 8)) = basis8(vv[q]);
      }
    } else {
#pragma unroll
      for (int q = 0; q < 4; ++q) {
        float4 u0 = pa[2 * q], u1 = pa[2 * q + 1];
        uint4 qq;
        qq.x = pk2(silu(u0.x), silu(u0.y));
        qq.y = pk2(silu(u0.z), silu(u0.w));
        qq.z = pk2(silu(u1.x), silu(u1.y));
        qq.w = pk2(silu(u1.z), silu(u1.w));
        int cc = sh * 4 + q;
        *(uint4*)(As + sr * 64 + ((cc ^ (sr & 7)) * 8)) = qq;
      }
    }
  };

  auto STAGEB = [&](int c) {
#pragma unroll
    for (int it = 0; it < 4; ++it) {
      int s = ltid + it * 256;
      int r_ = s >> 3, cc = (s & 7) ^ (r_ & 7);
      const u16* gp = Bp + (size_t)(n0 + r_) * K_TOT + c * 64 + cc * 8;
      __builtin_amdgcn_global_load_lds((const __attribute__((address_space(1))) void*)gp,
                                       (__attribute__((address_space(3))) void*)(Bs + s * 8),
                                       16, 0, 0);
    }
  };

  LOADX(cs);
  for (int c = cs; c < c1; ++c) {
    BUILD(c);
    STAGEB(c);
    if (c + 1 < c1) LOADX(c + 1);
    __syncthreads();
#pragma unroll
    for (int h = 0; h < 2; ++h) {
      short8 af[4], bf[4];
#pragma unroll
      for (int t = 0; t < 4; ++t) {
        af[t] = *(const short8*)(As + a_off[h][t]);
        bf[t] = *(const short8*)(Bs + b_off[h][t]);
      }
#pragma unroll
      for (int i = 0; i < 4; ++i)
#pragma unroll
        for (int j = 0; j < 4; ++j)
          acc[i][j] = __builtin_amdgcn_mfma_f32_16x16x32_bf16(af[i], bf[j], acc[i][j], 0, 0, 0);
    }
    __syncthreads();
  }

  // ---- intra-block reduce: group1 -> LDS -> group0 adds ----
  __syncthreads();
  float4* R = (float4*)smem;          // 4096 float4 = 64 KB
  if (g == 1) {
#pragma unroll
    for (int i = 0; i < 4; ++i)
#pragma unroll
      for (int j = 0; j < 4; ++j) {
        int k = i * 4 + j;
        R[ltid * 16 + (k ^ (ltid & 15))] = *(float4*)&acc[i][j];
      }
  }
  __syncthreads();
  if (g == 0) {
    const int lc = lane & 15;
    const int lr = (lane >> 4) * 4;
#pragma unroll
    for (int i = 0; i < 4; ++i) {
#pragma unroll
      for (int j = 0; j < 4; ++j) {
        int k = i * 4 + j;
        float4 o = R[ltid * 16 + (k ^ (ltid & 15))];
        acc[i][j][0] += o.x; acc[i][j][1] += o.y;
        acc[i][j][2] += o.z; acc[i][j][3] += o.w;
        int gr = row0 + wm * 64 + i * 16 + lr;
        int gc = n0 + wn * 64 + j * 16 + lc;
        float* po = out + (size_t)gr * N_COLS + gc;
#pragma unroll
        for (int r = 0; r < 4; ++r)
          unsafeAtomicAdd(po + (size_t)r * N_COLS, acc[i][j][r]);
      }
    }
  }
}

extern "C" void kernel_launch(void* const* d_in, const int* in_sizes, int n_in,
                              void* d_out, int out_size, void* d_ws, size_t ws_size,
                              hipStream_t stream) {
  const float* x  = (const float*)d_in[0];   // 16384 x 1024
  const float* bw = (const float*)d_in[1];   // 256 x 1024
  const float* sw = (const float*)d_in[2];   // 256 x 8192
  float* out = (float*)d_out;                // 16384 x 256 f32
  u16* Bp = (u16*)d_ws;                      // 256 x 9216 bf16 = 4.5 MB

  hipMemsetAsync(d_out, 0, (size_t)M_ROWS * N_COLS * sizeof(float), stream);

  dim3 pgrid(K_TOT / 4 / 256, N_COLS);       // (9, 256)
  pack_weights<<<pgrid, 256, 0, stream>>>(bw, sw, Bp);

  kan_gemm<<<512, 512, 0, stream>>>(x, Bp, out);
}

// Round 4
// 213.202 us; speedup vs baseline: 4.0693x; 1.6513x over previous
//
#include <hip/hip_runtime.h>
#include <cstdint>
#include <cstddef>

typedef unsigned short u16;
typedef unsigned int   u32;
typedef unsigned long long u64;
typedef __attribute__((ext_vector_type(8))) short short8;   // 8 bf16 = 4 VGPR
typedef __attribute__((ext_vector_type(4))) float f32x4;

#define M_ROWS 16384
#define N_COLS 256
#define IN_F   1024
#define K_SPL  8192   // 1024 features * 8 basis
#define K_TOT  9216   // + 1024 base (silu) features
// BK=64 chunks: 144 total (128 spline chunks of 8 features, 16 base chunks of 64 feats)
#define NCHUNK 144
#define SPLITK 2
#define CPB    (NCHUNK / SPLITK)   // 72 chunks per block

// ---------- helpers ----------
__device__ __forceinline__ u32 f2bf1(float f) {          // f32 -> bf16 bits, RNE
  u32 u = __float_as_uint(f);
  u += 0x7fffu + ((u >> 16) & 1u);
  return u >> 16;
}
__device__ __forceinline__ u32 pk2(float a, float b) {
  return f2bf1(a) | (f2bf1(b) << 16);
}
__device__ __forceinline__ float silu(float v) {
  return v * __builtin_amdgcn_rcpf(1.f + __expf(-v));
}

// 8 bf16 cubic B-spline basis values for one x, packed as uint4 (16B).
// u = 2.5x + 5.5; basis_j(x) = N3(u - j); 4 nonzero wts scattered via funnel shift.
__device__ __forceinline__ uint4 basis8(float xv) {
  float u = fmaf(xv, 2.5f, 5.5f);
  int i0 = (int)u;
  float fr = u - (float)i0;
  float fr2 = fr * fr, fr3 = fr2 * fr;
  float om  = 1.f - fr;
  float om3 = om * om * om;
  float w0 = om3 * (1.f / 6.f);
  float w3 = fr3 * (1.f / 6.f);
  float w1 = fmaf(fr3, 0.5f, fmaf(fr2, -1.f, 2.f / 3.f));
  float w2 = fmaf(fr + fr2 - fr3, 0.5f, 1.f / 6.f);
  u64 W = (u64)pk2(w0, w1) | ((u64)pk2(w2, w3) << 32);
  if (!(u >= 0.f && u < 11.f)) W = 0ull;
  int s = (i0 - 3) * 16;
  u64 lo, hi;
  if (s >= 64)      { int r = s - 64; lo = 0ull; hi = (r < 64) ? (W << r) : 0ull; }
  else if (s > 0)   { lo = W << s;    hi = W >> (64 - s); }
  else if (s == 0)  { lo = W;         hi = 0ull; }
  else              { int r = -s;     lo = (r < 64) ? (W >> r) : 0ull; hi = 0ull; }
  uint4 o;
  o.x = (u32)lo; o.y = (u32)(lo >> 32); o.z = (u32)hi; o.w = (u32)(hi >> 32);
  return o;
}

// ---------- kernel 1: pack [spline_weight | base_weight] -> bf16, (256 x 9216) row-major ----------
__global__ void pack_weights(const float* __restrict__ bw, const float* __restrict__ sw,
                             u16* __restrict__ Bp) {
  int o  = blockIdx.y;
  int k4 = (blockIdx.x * blockDim.x + threadIdx.x) * 4;
  const float* src = (k4 < K_SPL) ? (sw + (size_t)o * K_SPL + k4)
                                  : (bw + (size_t)o * IN_F + (k4 - K_SPL));
  float a = src[0], b = src[1], c = src[2], d = src[3];
  uint2 v; v.x = pk2(a, b); v.y = pk2(c, d);
  *(uint2*)(Bp + (size_t)o * K_TOT + k4) = v;
}

// ---------- kernel 2: fused KAN GEMM ----------
// BM=64 BN=256(=N, full width!) BK=64; 512 thr = 8 waves of 32m x 64n (acc 2x4).
// split-K=2, kid = bid&1 (adjacent partner blocks; R1-proven: WRITE = 2x out).
// grid 512 -> 2 independent blocks/CU (independent barrier domains hide each
// other's vmcnt(0) drains), 32 waves/CU thread-slot max.
// Each x element is loaded & basis-built exactly ONCE device-wide (BN covers all N).
// LDS 16B-chunk swizzle: chunk c of row r at slot r*8 + (c ^ (r&7)).
__global__ __launch_bounds__(512, 4)
void kan_gemm(const float* __restrict__ x, const u16* __restrict__ Bp,
              float* __restrict__ out) {
  __shared__ __align__(16) u16 As[64 * 64];    //  8 KB
  __shared__ __align__(16) u16 Bs[256 * 64];   // 32 KB

  const int tid  = threadIdx.x;
  const int lane = tid & 63;
  const int w    = tid >> 6;          // 0..7
  const int wm   = w & 1;             // m-half (32 rows)
  const int wn   = w >> 1;            // n-quarter (64 cols)

  const int bid  = blockIdx.x;        // 512
  const int kid  = bid & 1;
  const int mb   = bid >> 1;          // 0..255
  const int row0 = mb * 64;
  const int cs   = kid * CPB, c1 = cs + CPB;

  f32x4 acc[2][4];
#pragma unroll
  for (int i = 0; i < 2; ++i)
#pragma unroll
    for (int j = 0; j < 4; ++j)
      acc[i][j] = (f32x4){0.f, 0.f, 0.f, 0.f};

  const int sr = tid >> 3;            // staging row 0..63
  const int sq = tid & 7;             // feature (spline) / 8-feat group (base)

  // fragment read offsets (u16 index), swizzled
  const int lm = lane & 15;
  const int kg = lane >> 4;
  int a_off[2][2], b_off[2][4];
#pragma unroll
  for (int h = 0; h < 2; ++h) {
    int c = h * 4 + kg;
#pragma unroll
    for (int i = 0; i < 2; ++i) {
      int ra = wm * 32 + i * 16 + lm;
      a_off[h][i] = ra * 64 + ((c ^ (ra & 7)) * 8);
    }
#pragma unroll
    for (int j = 0; j < 4; ++j) {
      int rb = wn * 64 + j * 16 + lm;
      b_off[h][j] = rb * 64 + ((c ^ (rb & 7)) * 8);
    }
  }

  float px;            // spline prefetch (1 feature/thread)
  float4 pb0, pb1;     // base prefetch (8 features/thread)

  auto LOADX = [&](int c) {
    if (c < 128) {
      px = x[(size_t)(row0 + sr) * IN_F + c * 8 + sq];
    } else {
      const float* xp = x + (size_t)(row0 + sr) * IN_F + (c - 128) * 64 + sq * 8;
      pb0 = *(const float4*)xp;
      pb1 = *(const float4*)(xp + 4);
    }
  };

  auto BUILD = [&](int c) {
    uint4 q;
    if (c < 128) {
      q = basis8(px);
    } else {
      q.x = pk2(silu(pb0.x), silu(pb0.y));
      q.y = pk2(silu(pb0.z), silu(pb0.w));
      q.z = pk2(silu(pb1.x), silu(pb1.y));
      q.w = pk2(silu(pb1.z), silu(pb1.w));
    }
    *(uint4*)(As + sr * 64 + ((sq ^ (sr & 7)) * 8)) = q;
  };

  auto STAGEB = [&](int c) {
#pragma unroll
    for (int it = 0; it < 4; ++it) {
      int s = tid + it * 512;
      int r_ = s >> 3, cc = (s & 7) ^ (r_ & 7);
      const u16* gp = Bp + (size_t)r_ * K_TOT + c * 64 + cc * 8;
      __builtin_amdgcn_global_load_lds((const __attribute__((address_space(1))) void*)gp,
                                       (__attribute__((address_space(3))) void*)(Bs + s * 8),
                                       16, 0, 0);
    }
  };

  LOADX(cs);
  for (int c = cs; c < c1; ++c) {
    BUILD(c);
    STAGEB(c);
    if (c + 1 < c1) LOADX(c + 1);
    __syncthreads();
#pragma unroll
    for (int h = 0; h < 2; ++h) {
      short8 af[2], bf[4];
#pragma unroll
      for (int i = 0; i < 2; ++i) af[i] = *(const short8*)(As + a_off[h][i]);
#pragma unroll
      for (int j = 0; j < 4; ++j) bf[j] = *(const short8*)(Bs + b_off[h][j]);
#pragma unroll
      for (int i = 0; i < 2; ++i)
#pragma unroll
        for (int j = 0; j < 4; ++j)
          acc[i][j] = __builtin_amdgcn_mfma_f32_16x16x32_bf16(af[i], bf[j], acc[i][j], 0, 0, 0);
    }
    __syncthreads();
  }

  // ---- epilogue: C/D layout col=lane&15, row=(lane>>4)*4+reg; split-K=2 -> atomic add ----
  const int lc = lane & 15;
  const int lr = (lane >> 4) * 4;
#pragma unroll
  for (int i = 0; i < 2; ++i) {
#pragma unroll
    for (int j = 0; j < 4; ++j) {
      int gr = row0 + wm * 32 + i * 16 + lr;
      int gc = wn * 64 + j * 16 + lc;
      float* po = out + (size_t)gr * N_COLS + gc;
#pragma unroll
      for (int r = 0; r < 4; ++r)
        unsafeAtomicAdd(po + (size_t)r * N_COLS, acc[i][j][r]);
    }
  }
}

extern "C" void kernel_launch(void* const* d_in, const int* in_sizes, int n_in,
                              void* d_out, int out_size, void* d_ws, size_t ws_size,
                              hipStream_t stream) {
  const float* x  = (const float*)d_in[0];   // 16384 x 1024
  const float* bw = (const float*)d_in[1];   // 256 x 1024
  const float* sw = (const float*)d_in[2];   // 256 x 8192
  float* out = (float*)d_out;                // 16384 x 256 f32
  u16* Bp = (u16*)d_ws;                      // 256 x 9216 bf16 = 4.5 MB

  hipMemsetAsync(d_out, 0, (size_t)M_ROWS * N_COLS * sizeof(float), stream);

  dim3 pgrid(K_TOT / 4 / 256, N_COLS);       // (9, 256)
  pack_weights<<<pgrid, 256, 0, stream>>>(bw, sw, Bp);

  kan_gemm<<<512, 512, 0, stream>>>(x, Bp, out);
}